// Round 10
// baseline (209.822 us; speedup 1.0000x reference)
//
#include <hip/hip_runtime.h>
#include <hip/hip_bf16.h>

typedef unsigned short u16;
typedef unsigned int   u32;
typedef __attribute__((ext_vector_type(8))) short s16x8;
typedef __attribute__((ext_vector_type(16))) float f32x16;

#define BN_EPS 1e-3f
// problem dims
#define NB 16
#define NC 64
#define NH 160
#define NW 160
#define HP 162   // padded H
#define WPD 162  // padded W

// workspace layout (bytes)
#define OFF_XT 0UL
#define SZ_XT  (16UL*162*162*64*2)     // 53,747,712  padded NHWC bf16
#define OFF_WT (OFF_XT + SZ_XT)
#define SZ_WT  (4UL*64*9*64*2)         // 294,912  [e][ch][pos][cio][co][8ci] bf16
#define OFF_SH (OFF_WT + SZ_WT)        // bn shift [4][64] f32
#define OFF_WE (OFF_SH + 1024UL)       // wexp [16][4] f32
#define OFF_GP (OFF_WE + 256UL)        // gpart [16][800][64] f32 (3.28 MB)

// conv_main LDS partition (dynamic, 80,640 B total -> 2 blocks/CU)
#define XSTRIDE 342
#define XLS_BYTES (8 * XSTRIDE * 16)   // 43,776
#define WLS_BYTES (2304 * 16)          // 36,864 = 36 k-octets x 64 co x 16 B
#define SMEM_TOTAL (XLS_BYTES + WLS_BYTES)

__device__ __forceinline__ u16 f2bf(float f) {
    u32 u = __builtin_bit_cast(u32, f);
    u += 0x7fffu + ((u >> 16) & 1u);   // round-to-nearest-even
    return (u16)(u >> 16);
}

// ---- fused prep: x transpose + router partials + border zero + weights ---
// grid 15,968 = 12,800 transpose + 2,592 border + 576 weight blocks
// weights: [e][ch][pos][cio][co][8ci] bf16, pos stores tap (p%3)*3+(p/3)
// (dx-major) with BN scale FOLDED IN: w' = w * gamma*rsqrt(var+eps).
__global__ void prep_all(const float* __restrict__ x, u16* __restrict__ xt,
                         float* __restrict__ gpart,
                         const float* __restrict__ cw, u16* __restrict__ wt,
                         const float* __restrict__ gamma, const float* __restrict__ beta,
                         const float* __restrict__ mean, const float* __restrict__ var,
                         float* __restrict__ shift) {
    __shared__ float tile[64][33];
    int blk = blockIdx.x;
    int t = threadIdx.x;
    if (blk >= 15392) {                // weight repack + BN fold
        int idx = (blk - 15392) * 256 + t;
        {
            int cin = idx & 7;
            int r = idx >> 3;
            int co = r & 63; r >>= 6;
            int cio = r & 3; r >>= 2;
            int pos = r % 9; r /= 9;
            int ch = r & 1;
            int e = r >> 1;
            int tsp = (pos % 3) * 3 + (pos / 3);   // spatial tap dy*3+dx
            int ci = ch * 32 + cio * 8 + cin;
            int ec = e * 64 + co;
            float sc = gamma[ec] * rsqrtf(var[ec] + BN_EPS);
            wt[idx] = f2bf(cw[(((long)ec) * 64 + ci) * 9 + tsp] * sc);
        }
        if (idx < 256) {
            float sc = gamma[idx] * rsqrtf(var[idx] + BN_EPS);
            shift[idx] = beta[idx] - mean[idx] * sc;
        }
        return;
    }
    if (blk >= 12800) {                // zero the 1-px halo border
        int bb = blk - 12800;          // 0..2591 = b*162 + hp
        int hp = bb % 162, b = bb / 162;
        u32* row = (u32*)xt + (((long)b * 162 + hp) * 162) * 32;
        if (hp == 0 || hp == 161) {
            for (int i = t; i < 162 * 32; i += 256) row[i] = 0u;
        } else if (t < 64) {
            int p = (t >> 5) ? 161 : 0;
            row[p * 32 + (t & 31)] = 0u;
        }
        return;
    }
    int wt5 = blk % 5;
    int tmp = blk / 5;
    int h = tmp % 160, b = tmp / 160;
    int w0 = wt5 * 32;
    int w = t & 31, c0 = t >> 5;       // c0 in 0..7
#pragma unroll
    for (int i = 0; i < 8; ++i) {
        int c = c0 + 8 * i;
        tile[c][w] = x[(((long)b * 64 + c) * 160 + h) * 160 + w0 + w];
    }
    __syncthreads();
    if (t < 64) {                      // per-channel partial sum over 32 w
        float s = 0.f;
#pragma unroll
        for (int wi = 0; wi < 32; ++wi) s += tile[t][wi];
        gpart[(((long)b * 800) + h * 5 + wt5) * 64 + t] = s;   // [b][i][c]
    }
    u32* xt32 = (u32*)xt;
    long base = ((((long)b * 162 + h + 1) * 162) + (w0 + 1)) * 32; // u32 index
#pragma unroll
    for (int j = 0; j < 4; ++j) {
        int idx = t + 256 * j;         // 0..1023
        int p = idx >> 5, cp = idx & 31;
        float v0 = tile[2 * cp][p], v1 = tile[2 * cp + 1][p];
        xt32[base + p * 32 + cp] = (u32)f2bf(v0) | ((u32)f2bf(v1) << 16);
    }
}

// ---- fused avg-pool finish + router: one block per batch (16 blocks) -----
// gpart is [b][i 800][c 64]: wave-coalesced reads (lane c fast).
__global__ void finish16(const float* __restrict__ gpart,
                         const float* __restrict__ fc1w, const float* __restrict__ fc2w,
                         const float* __restrict__ fc2b, float* __restrict__ wexp) {
    __shared__ float part[256];
    __shared__ float gl[64];
    __shared__ float h1[16];
    int b = blockIdx.x, t = threadIdx.x;
    int c = t & 63, q = t >> 6;        // q = i-subset 0..3
    const float* gp = gpart + (long)b * 800 * 64;
    float s = 0.f;
    for (int i = q; i < 800; i += 4) s += gp[i * 64 + c];
    part[t] = s;
    __syncthreads();
    if (t < 64)
        gl[t] = (part[t] + part[t + 64] + part[t + 128] + part[t + 192])
                * (1.f / 25600.f);
    __syncthreads();
    if (t < 16) {
        float v = 0.f;
#pragma unroll
        for (int c2 = 0; c2 < 64; ++c2) v += gl[c2] * fc1w[t * 64 + c2];
        h1[t] = fmaxf(v, 0.f);
    }
    __syncthreads();
    if (t == 0) {
        float z[4];
#pragma unroll
        for (int e = 0; e < 4; ++e) {
            float v = fc2b[e];
#pragma unroll
            for (int r = 0; r < 16; ++r) v += h1[r] * fc2w[e * 16 + r];
            z[e] = v;
        }
        float m = fmaxf(fmaxf(z[0], z[1]), fmaxf(z[2], z[3]));
        float e0 = __expf(z[0] - m), e1 = __expf(z[1] - m);
        float e2 = __expf(z[2] - m), e3 = __expf(z[3] - m);
        float inv = 1.f / (e0 + e1 + e2 + e3);
        wexp[b * 4 + 0] = e0 * inv; wexp[b * 4 + 1] = e1 * inv;
        wexp[b * 4 + 2] = e2 * inv; wexp[b * 4 + 3] = e3 * inv;
    }
}

// ---- main: 4-expert implicit-GEMM conv + BN + SiLU + weighted sum --------
// grid 1600 ; block 256 (4 waves). Wave tile 64co x 64px via 32x32x16 MFMA.
// dx-grouped B-reuse (24 B + 36 A ds_read_b128 per stage). 3-phase counted
// vmcnt: group0 @ vmcnt(6), group1 @ vmcnt(3), group2 @ vmcnt(0) -- each
// wait covered by the previous group's MFMAs. BN scale pre-folded into wt.
__global__ __launch_bounds__(256, 2) void conv_main(
    const u16* __restrict__ xt, const u16* __restrict__ wt,
    const float* __restrict__ shift,
    const float* __restrict__ wexp, float* __restrict__ out) {
    extern __shared__ char smem[];
    u16* xls = (u16*)smem;                       // [cg 8][P @342] octets
    u16* wls = (u16*)(smem + XLS_BYTES);         // [pos*4+cio 36][co 64] octets

    // bijective chunked XCD swizzle (1600 % 8 == 0)
    const int o = blockIdx.x;
    const int blk = (o & 7) * 200 + (o >> 3);
    const int wt5 = blk % 5;
    const int tmp = blk / 5;
    const int ht = tmp % 20;
    const int b = tmp / 20;
    const int h0 = ht * 8, w0 = wt5 * 32;
    const int tid = threadIdx.x;
    const int lane = tid & 63;
    const int wv = tid >> 6;
    const int l31 = lane & 31, kh = lane >> 5;
    const int r0 = 2 * wv;                       // wave's two output rows

    // issue s=0 weight DMA first: lands under the x-staging latency
    {
#pragma unroll
        for (int r = 0; r < 9; ++r) {
            int oo = r * 256 + tid;
            __builtin_amdgcn_global_load_lds(
                (const __attribute__((address_space(1))) void*)(wt + oo * 8),
                (__attribute__((address_space(3))) void*)(wls + oo * 8),
                16, 0, 0);
        }
    }
    // stage x halo tile (rows h0..h0+9, cols w0..w0+33) into [cg][P@342]
    {
        const u16* xb = xt + (long)b * HP * WPD * 64;
        for (int c = tid; c < 2720; c += 256) {
            int P = c >> 3, cg = c & 7;
            int y = P / 34, px = P - y * 34;
            const u16* src = xb + (((long)(h0 + y) * WPD) + (w0 + px)) * 64 + cg * 8;
            s16x8 v = *(const s16x8*)src;
            *(s16x8*)(&xls[(cg * XSTRIDE + P) << 3]) = v;
        }
    }

    // address bases (u16 indices)
    const int oA2 = (kh * 64 + l31) << 3;        // + pos*2048 + ks*1024 + m2*256
    const int oBk0 = ((kh * XSTRIDE) + r0 * 34 + l31) << 3;          // ks=0
    const int oBk1 = oBk0 + ((2 * XSTRIDE) << 3);                    // ks=1

    f32x16 acc00 = (f32x16)(0.f), acc01 = (f32x16)(0.f);
    f32x16 acc10 = (f32x16)(0.f), acc11 = (f32x16)(0.f);
    f32x16 oac00 = (f32x16)(0.f), oac01 = (f32x16)(0.f);
    f32x16 oac10 = (f32x16)(0.f), oac11 = (f32x16)(0.f);

    auto epi = [&](int E) {
        const float we = wexp[(b << 2) + E];
        const float* shE = shift + (E << 6);
#pragma unroll
        for (int j = 0; j < 16; ++j) {
            const int cob = (j & 3) + 8 * (j >> 2) + 4 * kh;
            {
                float sh = shE[cob];
                float y0 = acc00[j] + sh;
                float y1 = acc01[j] + sh;
                oac00[j] += we * (y0 * __builtin_amdgcn_rcpf(1.f + __expf(-y0)));
                oac01[j] += we * (y1 * __builtin_amdgcn_rcpf(1.f + __expf(-y1)));
            }
            {
                float sh = shE[cob + 32];
                float y0 = acc10[j] + sh;
                float y1 = acc11[j] + sh;
                oac10[j] += we * (y0 * __builtin_amdgcn_rcpf(1.f + __expf(-y0)));
                oac11[j] += we * (y1 * __builtin_amdgcn_rcpf(1.f + __expf(-y1)));
            }
        }
        acc00 = (f32x16)(0.f); acc01 = (f32x16)(0.f);
        acc10 = (f32x16)(0.f); acc11 = (f32x16)(0.f);
    };

#pragma unroll 1
    for (int s = 0; s < 8; ++s) {
        const int ch = s & 1;
        if (s > 0) {
            __syncthreads();           // wls safe to overwrite
            const u16* wsrc = wt + ((long)s) * 2304 * 8;
#pragma unroll
            for (int r = 0; r < 9; ++r) {
                int oo = r * 256 + tid;
                __builtin_amdgcn_global_load_lds(
                    (const __attribute__((address_space(1))) void*)(wsrc + oo * 8),
                    (__attribute__((address_space(3))) void*)(wls + oo * 8),
                    16, 0, 0);
            }
        }
        const int chU = (ch * 4 * XSTRIDE) << 3;
        const int b0U = oBk0 + chU;              // ks=0 base for this ch
        const int b1U = oBk1 + chU;              // ks=1 base for this ch

        // one dx-group: 8 B-frag loads (rows r0..r0+3 x ks) -> 3 taps
        auto dx_group = [&](int g, int pos0) {
            const int gU = g << 3;               // dx offset (u16 units)
            s16x8 B00 = *(const s16x8*)(&xls[b0U + gU]);             // row0 ks0
            s16x8 B01 = *(const s16x8*)(&xls[b1U + gU]);             // row0 ks1
            s16x8 B10 = *(const s16x8*)(&xls[b0U + gU + (34 << 3)]);
            s16x8 B11 = *(const s16x8*)(&xls[b1U + gU + (34 << 3)]);
            s16x8 B20 = *(const s16x8*)(&xls[b0U + gU + (68 << 3)]);
            s16x8 B21 = *(const s16x8*)(&xls[b1U + gU + (68 << 3)]);
            s16x8 B30 = *(const s16x8*)(&xls[b0U + gU + (102 << 3)]);
            s16x8 B31 = *(const s16x8*)(&xls[b1U + gU + (102 << 3)]);
#pragma unroll
            for (int dy = 0; dy < 3; ++dy) {
                const int atU = oA2 + (pos0 + dy) * 2048;
                s16x8 a00 = *(const s16x8*)(&wls[atU]);          // m2=0 ks=0
                s16x8 a10 = *(const s16x8*)(&wls[atU + 256]);    // m2=1 ks=0
                s16x8 a01 = *(const s16x8*)(&wls[atU + 1024]);   // m2=0 ks=1
                s16x8 a11 = *(const s16x8*)(&wls[atU + 1280]);   // m2=1 ks=1
                s16x8 bn00 = (dy == 0) ? B00 : (dy == 1) ? B10 : B20; // n2=0 ks0
                s16x8 bn01 = (dy == 0) ? B01 : (dy == 1) ? B11 : B21; // n2=0 ks1
                s16x8 bn10 = (dy == 0) ? B10 : (dy == 1) ? B20 : B30; // n2=1 ks0
                s16x8 bn11 = (dy == 0) ? B11 : (dy == 1) ? B21 : B31; // n2=1 ks1
                acc00 = __builtin_amdgcn_mfma_f32_32x32x16_bf16(a00, bn00, acc00, 0, 0, 0);
                acc10 = __builtin_amdgcn_mfma_f32_32x32x16_bf16(a10, bn00, acc10, 0, 0, 0);
                acc01 = __builtin_amdgcn_mfma_f32_32x32x16_bf16(a00, bn10, acc01, 0, 0, 0);
                acc11 = __builtin_amdgcn_mfma_f32_32x32x16_bf16(a10, bn10, acc11, 0, 0, 0);
                acc00 = __builtin_amdgcn_mfma_f32_32x32x16_bf16(a01, bn01, acc00, 0, 0, 0);
                acc10 = __builtin_amdgcn_mfma_f32_32x32x16_bf16(a11, bn01, acc10, 0, 0, 0);
                acc01 = __builtin_amdgcn_mfma_f32_32x32x16_bf16(a01, bn11, acc01, 0, 0, 0);
                acc11 = __builtin_amdgcn_mfma_f32_32x32x16_bf16(a11, bn11, acc11, 0, 0, 0);
            }
        };

        // phase A: group 0 needs DMA rounds 0-2 only
        if (s == 0) __builtin_amdgcn_s_waitcnt(0x070);   // vmcnt(0) lgkmcnt(0)
        else        __builtin_amdgcn_s_waitcnt(0xF76);   // vmcnt(6)
        __builtin_amdgcn_s_barrier();
        __builtin_amdgcn_sched_barrier(0);
        dx_group(0, 0);

        // phase B: group 1 needs rounds 3-5
        __builtin_amdgcn_s_waitcnt(0xF73);               // vmcnt(3)
        __builtin_amdgcn_s_barrier();
        __builtin_amdgcn_sched_barrier(0);
        dx_group(1, 3);

        // phase C: group 2 after full drain
        __builtin_amdgcn_s_waitcnt(0xF70);               // vmcnt(0)
        __builtin_amdgcn_s_barrier();
        __builtin_amdgcn_sched_barrier(0);
        dx_group(2, 6);

        if (ch == 1) epi(s >> 1);      // after expert completes
    }

    // store NCHW f32: per instr 32 consecutive px x 2 co (128 B segments)
    const int yy = h0 + r0;
#pragma unroll
    for (int j = 0; j < 16; ++j) {
        const int cob = (j & 3) + 8 * (j >> 2) + 4 * kh;
        out[(((long)(b * 64 + cob)) * 160 + yy) * 160 + w0 + l31] = oac00[j];
        out[(((long)(b * 64 + cob)) * 160 + yy + 1) * 160 + w0 + l31] = oac01[j];
        out[(((long)(b * 64 + cob + 32)) * 160 + yy) * 160 + w0 + l31] = oac10[j];
        out[(((long)(b * 64 + cob + 32)) * 160 + yy + 1) * 160 + w0 + l31] = oac11[j];
    }
}

extern "C" void kernel_launch(void* const* d_in, const int* in_sizes, int n_in,
                              void* d_out, int out_size, void* d_ws, size_t ws_size,
                              hipStream_t stream) {
    const float* x = (const float*)d_in[0];
    const float* fc1w = (const float*)d_in[1];
    const float* fc2w = (const float*)d_in[2];
    const float* fc2b = (const float*)d_in[3];
    const float* convw = (const float*)d_in[4];
    const float* gamma = (const float*)d_in[5];
    const float* beta = (const float*)d_in[6];
    const float* mean = (const float*)d_in[7];
    const float* var = (const float*)d_in[8];
    float* out = (float*)d_out;
    char* ws = (char*)d_ws;
    u16* xt = (u16*)(ws + OFF_XT);
    u16* wtb = (u16*)(ws + OFF_WT);
    float* shift = (float*)(ws + OFF_SH);
    float* wexp = (float*)(ws + OFF_WE);
    float* gpart = (float*)(ws + OFF_GP);

    hipFuncSetAttribute((const void*)conv_main,
                        hipFuncAttributeMaxDynamicSharedMemorySize, SMEM_TOTAL);

    prep_all<<<15968, 256, 0, stream>>>(x, xt, gpart, convw, wtb,
                                        gamma, beta, mean, var, shift);
    finish16<<<16, 256, 0, stream>>>(gpart, fc1w, fc2w, fc2b, wexp);
    conv_main<<<1600, 256, SMEM_TOTAL, stream>>>(xt, wtb, shift, wexp, out);
}

// Round 11
// 180.113 us; speedup vs baseline: 1.1649x; 1.1649x over previous
//
#include <hip/hip_runtime.h>
#include <hip/hip_bf16.h>

typedef unsigned short u16;
typedef unsigned int   u32;
typedef __attribute__((ext_vector_type(8))) short s16x8;
typedef __attribute__((ext_vector_type(16))) float f32x16;

#define BN_EPS 1e-3f
// problem dims
#define NB 16
#define NC 64
#define NH 160
#define NW 160
#define HP 162   // padded H
#define WPD 162  // padded W

// workspace layout (bytes)
#define OFF_XT 0UL
#define SZ_XT  (16UL*162*162*64*2)     // 53,747,712  padded NHWC bf16
#define OFF_WT (OFF_XT + SZ_XT)
#define SZ_WT  (4UL*64*9*64*2)         // 294,912  [e][ch][pos][cio][co][8ci] bf16
#define OFF_SH (OFF_WT + SZ_WT)        // bn shift [4][64] f32
#define OFF_G  (OFF_SH + 1024UL)       // g [16][64] f32
#define OFF_WE (OFF_G + 4096UL)        // wexp [16][4] f32
#define OFF_GP (OFF_WE + 256UL)        // gpart [1024][800] f32 (3.28 MB)

// conv_main LDS partition (dynamic, 80,640 B total -> 2 blocks/CU)
#define XSTRIDE 342
#define XLS_BYTES (8 * XSTRIDE * 16)   // 43,776
#define WLS_BYTES (2304 * 16)          // 36,864 = 36 k-octets x 64 co x 16 B
#define SMEM_TOTAL (XLS_BYTES + WLS_BYTES)

__device__ __forceinline__ u16 f2bf(float f) {
    u32 u = __builtin_bit_cast(u32, f);
    u += 0x7fffu + ((u >> 16) & 1u);   // round-to-nearest-even
    return (u16)(u >> 16);
}

// ---- weights -> [e][ch][pos][cio][co][8ci] bf16, dx-major, BN-scale folded
__global__ void prep_w(const float* __restrict__ cw, u16* __restrict__ wt,
                       const float* __restrict__ gamma, const float* __restrict__ beta,
                       const float* __restrict__ mean, const float* __restrict__ var,
                       float* __restrict__ shift) {
    int idx = blockIdx.x * 256 + threadIdx.x;
    if (idx < 4 * 2 * 9 * 4 * 64 * 8) {
        int cin = idx & 7;
        int t = idx >> 3;
        int co = t & 63; t >>= 6;
        int cio = t & 3; t >>= 2;
        int pos = t % 9; t /= 9;
        int ch = t & 1;
        int e = t >> 1;
        int tsp = (pos % 3) * 3 + (pos / 3);   // spatial tap dy*3+dx
        int ci = ch * 32 + cio * 8 + cin;
        int ec = e * 64 + co;
        float sc = gamma[ec] * rsqrtf(var[ec] + BN_EPS);
        wt[idx] = f2bf(cw[(((long)ec) * 64 + ci) * 9 + tsp] * sc);
    }
    if (idx < 256) {
        float sc = gamma[idx] * rsqrtf(var[idx] + BN_EPS);
        shift[idx] = beta[idx] - mean[idx] * sc;
    }
}

// ---- x NCHW f32 -> padded NHWC bf16 + router partials + border zero ------
__global__ void prep_x(const float* __restrict__ x, u16* __restrict__ xt,
                       float* __restrict__ gpart) {
    __shared__ float tile[64][33];
    int blk = blockIdx.x;
    int t = threadIdx.x;
    if (blk >= 12800) {                // zero the 1-px halo border
        int bb = blk - 12800;          // 0..2591 = b*162 + hp
        int hp = bb % 162, b = bb / 162;
        u32* row = (u32*)xt + (((long)b * 162 + hp) * 162) * 32;
        if (hp == 0 || hp == 161) {
            for (int i = t; i < 162 * 32; i += 256) row[i] = 0u;
        } else if (t < 64) {
            int p = (t >> 5) ? 161 : 0;
            row[p * 32 + (t & 31)] = 0u;
        }
        return;
    }
    int wt5 = blk % 5;
    int tmp = blk / 5;
    int h = tmp % 160, b = tmp / 160;
    int w0 = wt5 * 32;
    int w = t & 31, c0 = t >> 5;       // c0 in 0..7
#pragma unroll
    for (int i = 0; i < 8; ++i) {
        int c = c0 + 8 * i;
        tile[c][w] = x[(((long)b * 64 + c) * 160 + h) * 160 + w0 + w];
    }
    __syncthreads();
    if (t < 64) {                      // per-channel partial sum over 32 w
        float s = 0.f;
#pragma unroll
        for (int wi = 0; wi < 32; ++wi) s += tile[t][wi];
        gpart[((long)(b * 64 + t)) * 800 + h * 5 + wt5] = s;
    }
    u32* xt32 = (u32*)xt;
    long base = ((((long)b * 162 + h + 1) * 162) + (w0 + 1)) * 32; // u32 index
#pragma unroll
    for (int j = 0; j < 4; ++j) {
        int idx = t + 256 * j;         // 0..1023
        int p = idx >> 5, cp = idx & 31;
        float v0 = tile[2 * cp][p], v1 = tile[2 * cp + 1][p];
        xt32[base + p * 32 + cp] = (u32)f2bf(v0) | ((u32)f2bf(v1) << 16);
    }
}

// ---- finish global average pool (1024 blocks: parallel, ~2 us) -----------
__global__ void g_reduce(const float* __restrict__ gpart, float* __restrict__ g) {
    int id = blockIdx.x;               // 1024 = b*64+c
    int t = threadIdx.x;
    float s = 0.f;
    for (int i = t; i < 800; i += 256) s += gpart[(long)id * 800 + i];
#pragma unroll
    for (int off = 32; off > 0; off >>= 1) s += __shfl_down(s, off, 64);
    __shared__ float red[4];
    if ((t & 63) == 0) red[t >> 6] = s;
    __syncthreads();
    if (t == 0) g[id] = (red[0] + red[1] + red[2] + red[3]) * (1.f / 25600.f);
}

// ---- router: fc1 -> relu -> fc2 -> softmax -------------------------------
__global__ void router(const float* __restrict__ g, const float* __restrict__ fc1w,
                       const float* __restrict__ fc2w, const float* __restrict__ fc2b,
                       float* __restrict__ wexp) {
    __shared__ float gL[16][64];
    __shared__ float h1[16][16];
    __shared__ float z[16][4];
    int t = threadIdx.x;
    for (int i = t; i < 1024; i += 256) gL[i >> 6][i & 63] = g[i];
    __syncthreads();
    {
        int b = t >> 4, r = t & 15;
        float s = 0.f;
#pragma unroll
        for (int c = 0; c < 64; ++c) s += gL[b][c] * fc1w[r * 64 + c];
        h1[b][r] = fmaxf(s, 0.f);
    }
    __syncthreads();
    if (t < 64) {
        int b = t >> 2, e = t & 3;
        float s = fc2b[e];
#pragma unroll
        for (int r = 0; r < 16; ++r) s += h1[b][r] * fc2w[e * 16 + r];
        z[b][e] = s;
    }
    __syncthreads();
    if (t < 16) {
        int b = t;
        float m = fmaxf(fmaxf(z[b][0], z[b][1]), fmaxf(z[b][2], z[b][3]));
        float e0 = __expf(z[b][0] - m), e1 = __expf(z[b][1] - m);
        float e2 = __expf(z[b][2] - m), e3 = __expf(z[b][3] - m);
        float inv = 1.f / (e0 + e1 + e2 + e3);
        wexp[b * 4 + 0] = e0 * inv; wexp[b * 4 + 1] = e1 * inv;
        wexp[b * 4 + 2] = e2 * inv; wexp[b * 4 + 3] = e3 * inv;
    }
}

// ---- main: 4-expert implicit-GEMM conv + BN + SiLU + weighted sum --------
// grid 1600 ; block 256 (4 waves). Wave tile 64co x 64px via 32x32x16 MFMA.
// dx-grouped B-reuse; 3-phase counted vmcnt; BN scale pre-folded into wt;
// T5: s_setprio(1) around each MFMA cluster (phase-split schedule).
__global__ __launch_bounds__(256, 2) void conv_main(
    const u16* __restrict__ xt, const u16* __restrict__ wt,
    const float* __restrict__ shift,
    const float* __restrict__ wexp, float* __restrict__ out) {
    extern __shared__ char smem[];
    u16* xls = (u16*)smem;                       // [cg 8][P @342] octets
    u16* wls = (u16*)(smem + XLS_BYTES);         // [pos*4+cio 36][co 64] octets

    // bijective chunked XCD swizzle (1600 % 8 == 0)
    const int o = blockIdx.x;
    const int blk = (o & 7) * 200 + (o >> 3);
    const int wt5 = blk % 5;
    const int tmp = blk / 5;
    const int ht = tmp % 20;
    const int b = tmp / 20;
    const int h0 = ht * 8, w0 = wt5 * 32;
    const int tid = threadIdx.x;
    const int lane = tid & 63;
    const int wv = tid >> 6;
    const int l31 = lane & 31, kh = lane >> 5;
    const int r0 = 2 * wv;                       // wave's two output rows

    // issue s=0 weight DMA first: lands under the x-staging latency
    {
#pragma unroll
        for (int r = 0; r < 9; ++r) {
            int oo = r * 256 + tid;
            __builtin_amdgcn_global_load_lds(
                (const __attribute__((address_space(1))) void*)(wt + oo * 8),
                (__attribute__((address_space(3))) void*)(wls + oo * 8),
                16, 0, 0);
        }
    }
    // stage x halo tile (rows h0..h0+9, cols w0..w0+33) into [cg][P@342]
    {
        const u16* xb = xt + (long)b * HP * WPD * 64;
        for (int c = tid; c < 2720; c += 256) {
            int P = c >> 3, cg = c & 7;
            int y = P / 34, px = P - y * 34;
            const u16* src = xb + (((long)(h0 + y) * WPD) + (w0 + px)) * 64 + cg * 8;
            s16x8 v = *(const s16x8*)src;
            *(s16x8*)(&xls[(cg * XSTRIDE + P) << 3]) = v;
        }
    }

    // address bases (u16 indices)
    const int oA2 = (kh * 64 + l31) << 3;        // + pos*2048 + ks*1024 + m2*256
    const int oBk0 = ((kh * XSTRIDE) + r0 * 34 + l31) << 3;          // ks=0
    const int oBk1 = oBk0 + ((2 * XSTRIDE) << 3);                    // ks=1

    f32x16 acc00 = (f32x16)(0.f), acc01 = (f32x16)(0.f);
    f32x16 acc10 = (f32x16)(0.f), acc11 = (f32x16)(0.f);
    f32x16 oac00 = (f32x16)(0.f), oac01 = (f32x16)(0.f);
    f32x16 oac10 = (f32x16)(0.f), oac11 = (f32x16)(0.f);

    auto epi = [&](int E) {
        const float we = wexp[(b << 2) + E];
        const float* shE = shift + (E << 6);
#pragma unroll
        for (int j = 0; j < 16; ++j) {
            const int cob = (j & 3) + 8 * (j >> 2) + 4 * kh;
            {
                float sh = shE[cob];
                float y0 = acc00[j] + sh;
                float y1 = acc01[j] + sh;
                oac00[j] += we * (y0 * __builtin_amdgcn_rcpf(1.f + __expf(-y0)));
                oac01[j] += we * (y1 * __builtin_amdgcn_rcpf(1.f + __expf(-y1)));
            }
            {
                float sh = shE[cob + 32];
                float y0 = acc10[j] + sh;
                float y1 = acc11[j] + sh;
                oac10[j] += we * (y0 * __builtin_amdgcn_rcpf(1.f + __expf(-y0)));
                oac11[j] += we * (y1 * __builtin_amdgcn_rcpf(1.f + __expf(-y1)));
            }
        }
        acc00 = (f32x16)(0.f); acc01 = (f32x16)(0.f);
        acc10 = (f32x16)(0.f); acc11 = (f32x16)(0.f);
    };

#pragma unroll 1
    for (int s = 0; s < 8; ++s) {
        const int ch = s & 1;
        if (s > 0) {
            __syncthreads();           // wls safe to overwrite
            const u16* wsrc = wt + ((long)s) * 2304 * 8;
#pragma unroll
            for (int r = 0; r < 9; ++r) {
                int oo = r * 256 + tid;
                __builtin_amdgcn_global_load_lds(
                    (const __attribute__((address_space(1))) void*)(wsrc + oo * 8),
                    (__attribute__((address_space(3))) void*)(wls + oo * 8),
                    16, 0, 0);
            }
        }
        const int chU = (ch * 4 * XSTRIDE) << 3;
        const int b0U = oBk0 + chU;              // ks=0 base for this ch
        const int b1U = oBk1 + chU;              // ks=1 base for this ch

        // one dx-group: 8 B-frag loads (rows r0..r0+3 x ks) -> 3 taps
        auto dx_group = [&](int g, int pos0) {
            const int gU = g << 3;               // dx offset (u16 units)
            s16x8 B00 = *(const s16x8*)(&xls[b0U + gU]);             // row0 ks0
            s16x8 B01 = *(const s16x8*)(&xls[b1U + gU]);             // row0 ks1
            s16x8 B10 = *(const s16x8*)(&xls[b0U + gU + (34 << 3)]);
            s16x8 B11 = *(const s16x8*)(&xls[b1U + gU + (34 << 3)]);
            s16x8 B20 = *(const s16x8*)(&xls[b0U + gU + (68 << 3)]);
            s16x8 B21 = *(const s16x8*)(&xls[b1U + gU + (68 << 3)]);
            s16x8 B30 = *(const s16x8*)(&xls[b0U + gU + (102 << 3)]);
            s16x8 B31 = *(const s16x8*)(&xls[b1U + gU + (102 << 3)]);
            __builtin_amdgcn_s_setprio(1);       // T5: favor MFMA wave
#pragma unroll
            for (int dy = 0; dy < 3; ++dy) {
                const int atU = oA2 + (pos0 + dy) * 2048;
                s16x8 a00 = *(const s16x8*)(&wls[atU]);          // m2=0 ks=0
                s16x8 a10 = *(const s16x8*)(&wls[atU + 256]);    // m2=1 ks=0
                s16x8 a01 = *(const s16x8*)(&wls[atU + 1024]);   // m2=0 ks=1
                s16x8 a11 = *(const s16x8*)(&wls[atU + 1280]);   // m2=1 ks=1
                s16x8 bn00 = (dy == 0) ? B00 : (dy == 1) ? B10 : B20; // n2=0 ks0
                s16x8 bn01 = (dy == 0) ? B01 : (dy == 1) ? B11 : B21; // n2=0 ks1
                s16x8 bn10 = (dy == 0) ? B10 : (dy == 1) ? B20 : B30; // n2=1 ks0
                s16x8 bn11 = (dy == 0) ? B11 : (dy == 1) ? B21 : B31; // n2=1 ks1
                acc00 = __builtin_amdgcn_mfma_f32_32x32x16_bf16(a00, bn00, acc00, 0, 0, 0);
                acc10 = __builtin_amdgcn_mfma_f32_32x32x16_bf16(a10, bn00, acc10, 0, 0, 0);
                acc01 = __builtin_amdgcn_mfma_f32_32x32x16_bf16(a00, bn10, acc01, 0, 0, 0);
                acc11 = __builtin_amdgcn_mfma_f32_32x32x16_bf16(a10, bn10, acc11, 0, 0, 0);
                acc00 = __builtin_amdgcn_mfma_f32_32x32x16_bf16(a01, bn01, acc00, 0, 0, 0);
                acc10 = __builtin_amdgcn_mfma_f32_32x32x16_bf16(a11, bn01, acc10, 0, 0, 0);
                acc01 = __builtin_amdgcn_mfma_f32_32x32x16_bf16(a01, bn11, acc01, 0, 0, 0);
                acc11 = __builtin_amdgcn_mfma_f32_32x32x16_bf16(a11, bn11, acc11, 0, 0, 0);
            }
            __builtin_amdgcn_s_setprio(0);
        };

        // phase A: group 0 needs DMA rounds 0-2 only
        if (s == 0) __builtin_amdgcn_s_waitcnt(0x070);   // vmcnt(0) lgkmcnt(0)
        else        __builtin_amdgcn_s_waitcnt(0xF76);   // vmcnt(6)
        __builtin_amdgcn_s_barrier();
        __builtin_amdgcn_sched_barrier(0);
        dx_group(0, 0);

        // phase B: group 1 needs rounds 3-5
        __builtin_amdgcn_s_waitcnt(0xF73);               // vmcnt(3)
        __builtin_amdgcn_s_barrier();
        __builtin_amdgcn_sched_barrier(0);
        dx_group(1, 3);

        // phase C: group 2 after full drain
        __builtin_amdgcn_s_waitcnt(0xF70);               // vmcnt(0)
        __builtin_amdgcn_s_barrier();
        __builtin_amdgcn_sched_barrier(0);
        dx_group(2, 6);

        if (ch == 1) epi(s >> 1);      // after expert completes
    }

    // store NCHW f32: per instr 32 consecutive px x 2 co (128 B segments)
    const int yy = h0 + r0;
#pragma unroll
    for (int j = 0; j < 16; ++j) {
        const int cob = (j & 3) + 8 * (j >> 2) + 4 * kh;
        out[(((long)(b * 64 + cob)) * 160 + yy) * 160 + w0 + l31] = oac00[j];
        out[(((long)(b * 64 + cob)) * 160 + yy + 1) * 160 + w0 + l31] = oac01[j];
        out[(((long)(b * 64 + cob + 32)) * 160 + yy) * 160 + w0 + l31] = oac10[j];
        out[(((long)(b * 64 + cob + 32)) * 160 + yy + 1) * 160 + w0 + l31] = oac11[j];
    }
}

extern "C" void kernel_launch(void* const* d_in, const int* in_sizes, int n_in,
                              void* d_out, int out_size, void* d_ws, size_t ws_size,
                              hipStream_t stream) {
    const float* x = (const float*)d_in[0];
    const float* fc1w = (const float*)d_in[1];
    const float* fc2w = (const float*)d_in[2];
    const float* fc2b = (const float*)d_in[3];
    const float* convw = (const float*)d_in[4];
    const float* gamma = (const float*)d_in[5];
    const float* beta = (const float*)d_in[6];
    const float* mean = (const float*)d_in[7];
    const float* var = (const float*)d_in[8];
    float* out = (float*)d_out;
    char* ws = (char*)d_ws;
    u16* xt = (u16*)(ws + OFF_XT);
    u16* wtb = (u16*)(ws + OFF_WT);
    float* shift = (float*)(ws + OFF_SH);
    float* g = (float*)(ws + OFF_G);
    float* wexp = (float*)(ws + OFF_WE);
    float* gpart = (float*)(ws + OFF_GP);

    hipFuncSetAttribute((const void*)conv_main,
                        hipFuncAttributeMaxDynamicSharedMemorySize, SMEM_TOTAL);

    prep_w<<<576, 256, 0, stream>>>(convw, wtb, gamma, beta, mean, var, shift);
    prep_x<<<15392, 256, 0, stream>>>(x, xt, gpart);
    g_reduce<<<1024, 256, 0, stream>>>(gpart, g);
    router<<<1, 256, 0, stream>>>(g, fc1w, fc2w, fc2b, wexp);
    conv_main<<<1600, 256, SMEM_TOTAL, stream>>>(xt, wtb, shift, wexp, out);
}

// Round 12
// 178.410 us; speedup vs baseline: 1.1761x; 1.0095x over previous
//
#include <hip/hip_runtime.h>
#include <hip/hip_bf16.h>

typedef unsigned short u16;
typedef unsigned int   u32;
typedef __attribute__((ext_vector_type(8))) short s16x8;
typedef __attribute__((ext_vector_type(16))) float f32x16;

#define BN_EPS 1e-3f
// problem dims
#define NB 16
#define NC 64
#define NH 160
#define NW 160
#define HP 162   // padded H
#define WPD 162  // padded W

// workspace layout (bytes)
#define OFF_XT 0UL
#define SZ_XT  (16UL*162*162*64*2)     // 53,747,712  padded NHWC bf16
#define OFF_WT (OFF_XT + SZ_XT)
#define SZ_WT  (4UL*64*9*64*2)         // 294,912  [e][ch][pos][cio][co][8ci] bf16
#define OFF_SH (OFF_WT + SZ_WT)        // bn shift [4][64] f32
#define OFF_G  (OFF_SH + 1024UL)       // g [16][64] f32
#define OFF_WE (OFF_G + 4096UL)        // wexp [16][4] f32
#define OFF_GP (OFF_WE + 256UL)        // gpart [1024][800] f32 (3.28 MB)

// conv_main LDS partition (dynamic, 81,664 B total -> 2 blocks/CU: 163,328 <= 163,840)
#define XSTRIDE 342
#define XLS_BYTES (8 * XSTRIDE * 16)   // 43,776
#define WLS_BYTES (2304 * 16)          // 36,864 = 36 k-octet rows x 64 co x 16 B
#define SHLS_BYTES 1024                // shift [4][64] f32 in LDS
#define SMEM_TOTAL (XLS_BYTES + WLS_BYTES + SHLS_BYTES)

__device__ __forceinline__ u16 f2bf(float f) {
    u32 u = __builtin_bit_cast(u32, f);
    u += 0x7fffu + ((u >> 16) & 1u);   // round-to-nearest-even
    return (u16)(u >> 16);
}

// ---- weights -> [e][ch][pos][cio][co][8ci] bf16, dx-major, BN-scale folded
__global__ void prep_w(const float* __restrict__ cw, u16* __restrict__ wt,
                       const float* __restrict__ gamma, const float* __restrict__ beta,
                       const float* __restrict__ mean, const float* __restrict__ var,
                       float* __restrict__ shift) {
    int idx = blockIdx.x * 256 + threadIdx.x;
    if (idx < 4 * 2 * 9 * 4 * 64 * 8) {
        int cin = idx & 7;
        int t = idx >> 3;
        int co = t & 63; t >>= 6;
        int cio = t & 3; t >>= 2;
        int pos = t % 9; t /= 9;
        int ch = t & 1;
        int e = t >> 1;
        int tsp = (pos % 3) * 3 + (pos / 3);   // spatial tap dy*3+dx
        int ci = ch * 32 + cio * 8 + cin;
        int ec = e * 64 + co;
        float sc = gamma[ec] * rsqrtf(var[ec] + BN_EPS);
        wt[idx] = f2bf(cw[(((long)ec) * 64 + ci) * 9 + tsp] * sc);
    }
    if (idx < 256) {
        float sc = gamma[idx] * rsqrtf(var[idx] + BN_EPS);
        shift[idx] = beta[idx] - mean[idx] * sc;
    }
}

// ---- x NCHW f32 -> padded NHWC bf16 + router partials + border zero ------
__global__ void prep_x(const float* __restrict__ x, u16* __restrict__ xt,
                       float* __restrict__ gpart) {
    __shared__ float tile[64][33];
    int blk = blockIdx.x;
    int t = threadIdx.x;
    if (blk >= 12800) {                // zero the 1-px halo border
        int bb = blk - 12800;          // 0..2591 = b*162 + hp
        int hp = bb % 162, b = bb / 162;
        u32* row = (u32*)xt + (((long)b * 162 + hp) * 162) * 32;
        if (hp == 0 || hp == 161) {
            for (int i = t; i < 162 * 32; i += 256) row[i] = 0u;
        } else if (t < 64) {
            int p = (t >> 5) ? 161 : 0;
            row[p * 32 + (t & 31)] = 0u;
        }
        return;
    }
    int wt5 = blk % 5;
    int tmp = blk / 5;
    int h = tmp % 160, b = tmp / 160;
    int w0 = wt5 * 32;
    int w = t & 31, c0 = t >> 5;       // c0 in 0..7
#pragma unroll
    for (int i = 0; i < 8; ++i) {
        int c = c0 + 8 * i;
        tile[c][w] = x[(((long)b * 64 + c) * 160 + h) * 160 + w0 + w];
    }
    __syncthreads();
    if (t < 64) {                      // per-channel partial sum over 32 w
        float s = 0.f;
#pragma unroll
        for (int wi = 0; wi < 32; ++wi) s += tile[t][wi];
        gpart[((long)(b * 64 + t)) * 800 + h * 5 + wt5] = s;
    }
    u32* xt32 = (u32*)xt;
    long base = ((((long)b * 162 + h + 1) * 162) + (w0 + 1)) * 32; // u32 index
#pragma unroll
    for (int j = 0; j < 4; ++j) {
        int idx = t + 256 * j;         // 0..1023
        int p = idx >> 5, cp = idx & 31;
        float v0 = tile[2 * cp][p], v1 = tile[2 * cp + 1][p];
        xt32[base + p * 32 + cp] = (u32)f2bf(v0) | ((u32)f2bf(v1) << 16);
    }
}

// ---- finish global average pool (1024 blocks: parallel, ~2 us) -----------
__global__ void g_reduce(const float* __restrict__ gpart, float* __restrict__ g) {
    int id = blockIdx.x;               // 1024 = b*64+c
    int t = threadIdx.x;
    float s = 0.f;
    for (int i = t; i < 800; i += 256) s += gpart[(long)id * 800 + i];
#pragma unroll
    for (int off = 32; off > 0; off >>= 1) s += __shfl_down(s, off, 64);
    __shared__ float red[4];
    if ((t & 63) == 0) red[t >> 6] = s;
    __syncthreads();
    if (t == 0) g[id] = (red[0] + red[1] + red[2] + red[3]) * (1.f / 25600.f);
}

// ---- router: fc1 -> relu -> fc2 -> softmax -------------------------------
__global__ void router(const float* __restrict__ g, const float* __restrict__ fc1w,
                       const float* __restrict__ fc2w, const float* __restrict__ fc2b,
                       float* __restrict__ wexp) {
    __shared__ float gL[16][64];
    __shared__ float h1[16][16];
    __shared__ float z[16][4];
    int t = threadIdx.x;
    for (int i = t; i < 1024; i += 256) gL[i >> 6][i & 63] = g[i];
    __syncthreads();
    {
        int b = t >> 4, r = t & 15;
        float s = 0.f;
#pragma unroll
        for (int c = 0; c < 64; ++c) s += gL[b][c] * fc1w[r * 64 + c];
        h1[b][r] = fmaxf(s, 0.f);
    }
    __syncthreads();
    if (t < 64) {
        int b = t >> 2, e = t & 3;
        float s = fc2b[e];
#pragma unroll
        for (int r = 0; r < 16; ++r) s += h1[b][r] * fc2w[e * 16 + r];
        z[b][e] = s;
    }
    __syncthreads();
    if (t < 16) {
        int b = t;
        float m = fmaxf(fmaxf(z[b][0], z[b][1]), fmaxf(z[b][2], z[b][3]));
        float e0 = __expf(z[b][0] - m), e1 = __expf(z[b][1] - m);
        float e2 = __expf(z[b][2] - m), e3 = __expf(z[b][3] - m);
        float inv = 1.f / (e0 + e1 + e2 + e3);
        wexp[b * 4 + 0] = e0 * inv; wexp[b * 4 + 1] = e1 * inv;
        wexp[b * 4 + 2] = e2 * inv; wexp[b * 4 + 3] = e3 * inv;
    }
}

// ---- main: 4-expert implicit-GEMM conv + BN + SiLU + weighted sum --------
// grid 1600 ; block 256 (4 waves). Wave tile 64co x 64px via 32x32x16 MFMA.
// CROSS-STAGE DMA prefetch: stage s+1's rounds 0-5 issued in s's phase B
// (rows 0-23 proven free by the barrier), rounds 6-8 after the stage-end
// barrier (rows 24-35 free). Every vmcnt wait lands >=1 compute phase after
// its issue. 2 compute phases per stage, 3 barriers/stage. Epilogue is
// VMEM-free (shift in LDS, wexp preloaded) so vmcnt counting stays exact.
__global__ __launch_bounds__(256, 2) void conv_main(
    const u16* __restrict__ xt, const u16* __restrict__ wt,
    const float* __restrict__ shift,
    const float* __restrict__ wexp, float* __restrict__ out) {
    extern __shared__ char smem[];
    u16* xls = (u16*)smem;                       // [cg 8][P @342] octets
    u16* wls = (u16*)(smem + XLS_BYTES);         // [pos*4+cio 36][co 64] octets
    float* shls = (float*)(smem + XLS_BYTES + WLS_BYTES);   // [4][64] f32

    // bijective chunked XCD swizzle (1600 % 8 == 0)
    const int o = blockIdx.x;
    const int blk = (o & 7) * 200 + (o >> 3);
    const int wt5 = blk % 5;
    const int tmp = blk / 5;
    const int ht = tmp % 20;
    const int b = tmp / 20;
    const int h0 = ht * 8, w0 = wt5 * 32;
    const int tid = threadIdx.x;
    const int lane = tid & 63;
    const int wv = tid >> 6;
    const int l31 = lane & 31, kh = lane >> 5;
    const int r0 = 2 * wv;                       // wave's two output rows

    // issue s=0 weight DMA first: lands under the x-staging latency
    {
#pragma unroll
        for (int r = 0; r < 9; ++r) {
            int oo = r * 256 + tid;
            __builtin_amdgcn_global_load_lds(
                (const __attribute__((address_space(1))) void*)(wt + oo * 8),
                (__attribute__((address_space(3))) void*)(wls + oo * 8),
                16, 0, 0);
        }
    }
    // preload router weights (4 regs) + shift into LDS (1 KB)
    const float we0 = wexp[(b << 2) + 0];
    const float we1 = wexp[(b << 2) + 1];
    const float we2 = wexp[(b << 2) + 2];
    const float we3 = wexp[(b << 2) + 3];
    shls[tid] = shift[tid];
    // stage x halo tile (rows h0..h0+9, cols w0..w0+33) into [cg][P@342]
    {
        const u16* xb = xt + (long)b * HP * WPD * 64;
        for (int c = tid; c < 2720; c += 256) {
            int P = c >> 3, cg = c & 7;
            int y = P / 34, px = P - y * 34;
            const u16* src = xb + (((long)(h0 + y) * WPD) + (w0 + px)) * 64 + cg * 8;
            s16x8 v = *(const s16x8*)src;
            *(s16x8*)(&xls[(cg * XSTRIDE + P) << 3]) = v;
        }
    }

    // address bases (u16 indices)
    const int oA2 = (kh * 64 + l31) << 3;        // + pos*2048 + ks*1024 + m2*256
    const int oBk0 = ((kh * XSTRIDE) + r0 * 34 + l31) << 3;          // ks=0
    const int oBk1 = oBk0 + ((2 * XSTRIDE) << 3);                    // ks=1

    f32x16 acc00 = (f32x16)(0.f), acc01 = (f32x16)(0.f);
    f32x16 acc10 = (f32x16)(0.f), acc11 = (f32x16)(0.f);
    f32x16 oac00 = (f32x16)(0.f), oac01 = (f32x16)(0.f);
    f32x16 oac10 = (f32x16)(0.f), oac11 = (f32x16)(0.f);

    auto epi = [&](int E) {
        const float we = (E == 0) ? we0 : (E == 1) ? we1 : (E == 2) ? we2 : we3;
        const float* shE = shls + (E << 6);      // LDS broadcast reads
#pragma unroll
        for (int j = 0; j < 16; ++j) {
            const int cob = (j & 3) + 8 * (j >> 2) + 4 * kh;
            {
                float sh = shE[cob];
                float y0 = acc00[j] + sh;
                float y1 = acc01[j] + sh;
                oac00[j] += we * (y0 * __builtin_amdgcn_rcpf(1.f + __expf(-y0)));
                oac01[j] += we * (y1 * __builtin_amdgcn_rcpf(1.f + __expf(-y1)));
            }
            {
                float sh = shE[cob + 32];
                float y0 = acc10[j] + sh;
                float y1 = acc11[j] + sh;
                oac10[j] += we * (y0 * __builtin_amdgcn_rcpf(1.f + __expf(-y0)));
                oac11[j] += we * (y1 * __builtin_amdgcn_rcpf(1.f + __expf(-y1)));
            }
        }
        acc00 = (f32x16)(0.f); acc01 = (f32x16)(0.f);
        acc10 = (f32x16)(0.f); acc11 = (f32x16)(0.f);
    };

#pragma unroll 1
    for (int s = 0; s < 8; ++s) {
        const int ch = s & 1;
        const int chU = (ch * 4 * XSTRIDE) << 3;
        const int b0U = oBk0 + chU;              // ks=0 base for this ch
        const int b1U = oBk1 + chU;              // ks=1 base for this ch

        // one dx-group: 8 B-frag loads (rows r0..r0+3 x ks) -> 3 taps
        auto dx_group = [&](int g, int pos0) {
            const int gU = g << 3;               // dx offset (u16 units)
            s16x8 B00 = *(const s16x8*)(&xls[b0U + gU]);             // row0 ks0
            s16x8 B01 = *(const s16x8*)(&xls[b1U + gU]);             // row0 ks1
            s16x8 B10 = *(const s16x8*)(&xls[b0U + gU + (34 << 3)]);
            s16x8 B11 = *(const s16x8*)(&xls[b1U + gU + (34 << 3)]);
            s16x8 B20 = *(const s16x8*)(&xls[b0U + gU + (68 << 3)]);
            s16x8 B21 = *(const s16x8*)(&xls[b1U + gU + (68 << 3)]);
            s16x8 B30 = *(const s16x8*)(&xls[b0U + gU + (102 << 3)]);
            s16x8 B31 = *(const s16x8*)(&xls[b1U + gU + (102 << 3)]);
            __builtin_amdgcn_s_setprio(1);
#pragma unroll
            for (int dy = 0; dy < 3; ++dy) {
                const int atU = oA2 + (pos0 + dy) * 2048;
                s16x8 a00 = *(const s16x8*)(&wls[atU]);          // m2=0 ks=0
                s16x8 a10 = *(const s16x8*)(&wls[atU + 256]);    // m2=1 ks=0
                s16x8 a01 = *(const s16x8*)(&wls[atU + 1024]);   // m2=0 ks=1
                s16x8 a11 = *(const s16x8*)(&wls[atU + 1280]);   // m2=1 ks=1
                s16x8 bn00 = (dy == 0) ? B00 : (dy == 1) ? B10 : B20; // n2=0 ks0
                s16x8 bn01 = (dy == 0) ? B01 : (dy == 1) ? B11 : B21; // n2=0 ks1
                s16x8 bn10 = (dy == 0) ? B10 : (dy == 1) ? B20 : B30; // n2=1 ks0
                s16x8 bn11 = (dy == 0) ? B11 : (dy == 1) ? B21 : B31; // n2=1 ks1
                acc00 = __builtin_amdgcn_mfma_f32_32x32x16_bf16(a00, bn00, acc00, 0, 0, 0);
                acc10 = __builtin_amdgcn_mfma_f32_32x32x16_bf16(a10, bn00, acc10, 0, 0, 0);
                acc01 = __builtin_amdgcn_mfma_f32_32x32x16_bf16(a00, bn10, acc01, 0, 0, 0);
                acc11 = __builtin_amdgcn_mfma_f32_32x32x16_bf16(a10, bn10, acc11, 0, 0, 0);
                acc00 = __builtin_amdgcn_mfma_f32_32x32x16_bf16(a01, bn01, acc00, 0, 0, 0);
                acc10 = __builtin_amdgcn_mfma_f32_32x32x16_bf16(a11, bn01, acc10, 0, 0, 0);
                acc01 = __builtin_amdgcn_mfma_f32_32x32x16_bf16(a01, bn11, acc01, 0, 0, 0);
                acc11 = __builtin_amdgcn_mfma_f32_32x32x16_bf16(a11, bn11, acc11, 0, 0, 0);
            }
            __builtin_amdgcn_s_setprio(0);
        };

        // phase A: dx-groups 0,1 (wls rows 0-23; DMA rounds 0-5 of stage s)
        if (s == 0) __builtin_amdgcn_s_waitcnt(0x070);   // vmcnt(0) lgkmcnt(0)
        else        __builtin_amdgcn_s_waitcnt(0xF73);   // vmcnt(3): rounds 0-5 done
        __builtin_amdgcn_s_barrier();
        __builtin_amdgcn_sched_barrier(0);
        dx_group(0, 0);
        dx_group(1, 3);

        // phase B: dx-group 2 (rows 24-35; rounds 6-8)
        __builtin_amdgcn_s_waitcnt(0xF70);               // vmcnt(0)
        __builtin_amdgcn_s_barrier();
        __builtin_amdgcn_sched_barrier(0);
        if (s < 7) {   // prefetch next stage rounds 0-5 (rows 0-23 free: all
                       // waves passed the phase-B barrier after reading them)
            const u16* wsrc = wt + ((long)(s + 1)) * 2304 * 8;
#pragma unroll
            for (int r = 0; r < 6; ++r) {
                int oo = r * 256 + tid;
                __builtin_amdgcn_global_load_lds(
                    (const __attribute__((address_space(1))) void*)(wsrc + oo * 8),
                    (__attribute__((address_space(3))) void*)(wls + oo * 8),
                    16, 0, 0);
            }
        }
        dx_group(2, 6);
        if (ch == 1) epi(s >> 1);      // pure VALU/LDS-broadcast, no VMEM

        __builtin_amdgcn_s_barrier();  // all waves done reading rows 24-35
        __builtin_amdgcn_sched_barrier(0);
        if (s < 7) {   // prefetch next stage rounds 6-8
            const u16* wsrc = wt + ((long)(s + 1)) * 2304 * 8;
#pragma unroll
            for (int r = 6; r < 9; ++r) {
                int oo = r * 256 + tid;
                __builtin_amdgcn_global_load_lds(
                    (const __attribute__((address_space(1))) void*)(wsrc + oo * 8),
                    (__attribute__((address_space(3))) void*)(wls + oo * 8),
                    16, 0, 0);
            }
        }
    }

    // store NCHW f32: per instr 32 consecutive px x 2 co (128 B segments)
    const int yy = h0 + r0;
#pragma unroll
    for (int j = 0; j < 16; ++j) {
        const int cob = (j & 3) + 8 * (j >> 2) + 4 * kh;
        out[(((long)(b * 64 + cob)) * 160 + yy) * 160 + w0 + l31] = oac00[j];
        out[(((long)(b * 64 + cob)) * 160 + yy + 1) * 160 + w0 + l31] = oac01[j];
        out[(((long)(b * 64 + cob + 32)) * 160 + yy) * 160 + w0 + l31] = oac10[j];
        out[(((long)(b * 64 + cob + 32)) * 160 + yy + 1) * 160 + w0 + l31] = oac11[j];
    }
}

extern "C" void kernel_launch(void* const* d_in, const int* in_sizes, int n_in,
                              void* d_out, int out_size, void* d_ws, size_t ws_size,
                              hipStream_t stream) {
    const float* x = (const float*)d_in[0];
    const float* fc1w = (const float*)d_in[1];
    const float* fc2w = (const float*)d_in[2];
    const float* fc2b = (const float*)d_in[3];
    const float* convw = (const float*)d_in[4];
    const float* gamma = (const float*)d_in[5];
    const float* beta = (const float*)d_in[6];
    const float* mean = (const float*)d_in[7];
    const float* var = (const float*)d_in[8];
    float* out = (float*)d_out;
    char* ws = (char*)d_ws;
    u16* xt = (u16*)(ws + OFF_XT);
    u16* wtb = (u16*)(ws + OFF_WT);
    float* shift = (float*)(ws + OFF_SH);
    float* g = (float*)(ws + OFF_G);
    float* wexp = (float*)(ws + OFF_WE);
    float* gpart = (float*)(ws + OFF_GP);

    hipFuncSetAttribute((const void*)conv_main,
                        hipFuncAttributeMaxDynamicSharedMemorySize, SMEM_TOTAL);

    prep_w<<<576, 256, 0, stream>>>(convw, wtb, gamma, beta, mean, var, shift);
    prep_x<<<15392, 256, 0, stream>>>(x, xt, gpart);
    g_reduce<<<1024, 256, 0, stream>>>(gpart, g);
    router<<<1, 256, 0, stream>>>(g, fc1w, fc2w, fc2b, wexp);
    conv_main<<<1600, 256, SMEM_TOTAL, stream>>>(xt, wtb, shift, wexp, out);
}